// Round 2
// baseline (536.171 us; speedup 1.0000x reference)
//
#include <hip/hip_runtime.h>

// ScaledDotProductAttention: b=16, n=2048, d=64, causal, temp=8.
// Outputs concatenated in d_out: out [b,n,d] fp32, attn [b,n,n] fp32.
//
// Round 4: two-kernel split to fix the 1-block/CU latency choke of round 3.
//  Kernel A (sdpa_flash): flash-style single pass. 512 thr / 8 waves per
//    (batch, 32 q-rows). Small per-tile LDS (23.7 KB -> 4 blocks/CU, 100%
//    occupancy cap). Accumulates unnormalized O and f32 row sums; writes
//    normalized `out` and 1/rowsum into the d_ws workspace.
//  Kernel B (sdpa_attn): recomputes S with SWAPPED MFMA operands
//    (mfma(Kfrag, Qfrag) -> C holds S^T: lane = one q-row, 4 consecutive k)
//    so normalized attn is written as one float4 per lane, no LDS transpose,
//    ZERO barriers in the k-loop. K-frags load directly from global (L2-hot).
//    Zero tail written in the same kernel; every block stores exactly 256 KB
//    -> pure balanced write stream.

constexpr int B = 16;
constexpr int N = 2048;
constexpr int D = 64;
constexpr float INV_TEMP = 0.125f; // 1/8

typedef __attribute__((ext_vector_type(8))) short bf16x8; // 8 bf16 in 4 VGPRs
typedef __attribute__((ext_vector_type(4))) float f32x4;

__device__ __forceinline__ short f2bf(float f) {
    __bf16 h = (__bf16)f;
    return __builtin_bit_cast(short, h);
}

// ---------------------------------------------------------------------------
// Kernel A: flash pass -> out + 1/rowsum workspace
// ---------------------------------------------------------------------------
__global__ __launch_bounds__(512) void sdpa_flash(
    const float* __restrict__ q,
    const float* __restrict__ k,
    const float* __restrict__ v,
    float* __restrict__ out,
    float* __restrict__ invws)
{
    __shared__ __align__(16) short sK[64][72];   // K tile (also Q stage)
    __shared__ __align__(16) short sV[64][72];   // V tile TRANSPOSED: sV[d][kr]
    __shared__ __align__(16) short sPt[32][72];  // per-tile P (bf16)
    __shared__ float rsum[128];                  // [8 waves][16 rows]
    __shared__ float sinv[32];

    const int x = blockIdx.x;
    const int b = x >> 6;                 // batch
    const int u = x & 63;
    const int rt = 63 - u;                // heavy row-blocks first
    const int qs = rt * 32;
    const int ntiles = (rt >> 1) + 1;     // 64-wide K tiles covering cols 0..qs+31

    const int t    = threadIdx.x;
    const int w    = t >> 6;              // wave 0..7
    const int lane = t & 63;
    const int l15  = lane & 15;
    const int quad = lane >> 4;           // 0..3
    const int q8   = quad * 8;
    const int rg   = w & 1;               // row-group (16 rows) of the 32-row tile
    const int cg   = w >> 1;              // col-group (16 cols) of the 64-col K tile

    const float* qb = q + (size_t)b * N * D;
    const float* kb = k + (size_t)b * N * D;
    const float* vb = v + (size_t)b * N * D;

    const int krow = t >> 3;              // staging row 0..63
    const int kc8  = (t & 7) * 8;         // staging d-chunk start (8 floats)

    float4 kf0, kf1;                      // K prefetch regs
    float  vr[8];                         // V prefetch regs

    // ---- prefetch K/V tile 0 into registers ----
    {
        const float4* s = (const float4*)(kb + (size_t)krow * D + kc8);
        kf0 = s[0]; kf1 = s[1];
        const float* sv = vb + (size_t)(w * 8) * D + lane;
#pragma unroll
        for (int i = 0; i < 8; ++i) vr[i] = sv[(size_t)i * D];
    }

    // ---- stage Q tile -> sK rows 0..31 (bf16), then A-frags to registers ----
    if (t < 256) {
        const float4* s = (const float4*)(qb + (size_t)(qs + krow) * D + kc8);
        float4 a = s[0], c4 = s[1];
        float qv[8] = {a.x,a.y,a.z,a.w, c4.x,c4.y,c4.z,c4.w};
        bf16x8 pq;
#pragma unroll
        for (int i = 0; i < 8; ++i) pq[i] = f2bf(qv[i]);
        *(bf16x8*)&sK[krow][kc8] = pq;
    }
    __syncthreads();
    const bf16x8 qa0 = *(const bf16x8*)&sK[rg * 16 + l15][q8];       // d 0..31
    const bf16x8 qa1 = *(const bf16x8*)&sK[rg * 16 + l15][32 + q8];  // d 32..63

    float rs[4] = {0.f, 0.f, 0.f, 0.f};
    f32x4 o = {0.f, 0.f, 0.f, 0.f};

    for (int kt = 0; kt < ntiles; ++kt) {
        __syncthreads();   // prev tile's PV reads (and kt=0 Q-frag reads) done
        {   // staged regs -> LDS (b128 writes)
            float kv[8] = {kf0.x,kf0.y,kf0.z,kf0.w, kf1.x,kf1.y,kf1.z,kf1.w};
            bf16x8 pk, pv;
#pragma unroll
            for (int i = 0; i < 8; ++i) pk[i] = f2bf(kv[i]);
#pragma unroll
            for (int i = 0; i < 8; ++i) pv[i] = f2bf(vr[i]);
            *(bf16x8*)&sK[krow][kc8]  = pk;          // K[kr][d]
            *(bf16x8*)&sV[lane][w*8]  = pv;          // V^T: sV[d][kr]
        }
        __syncthreads();
        // T14: issue next tile's global loads; latency hides under S+PV
        if (kt + 1 < ntiles) {
            const float4* s = (const float4*)(kb + (size_t)((kt+1)*64 + krow) * D + kc8);
            kf0 = s[0]; kf1 = s[1];
            const float* sv = vb + (size_t)((kt+1)*64 + w*8) * D + lane;
#pragma unroll
            for (int i = 0; i < 8; ++i) vr[i] = sv[(size_t)i * D];
        }
        // S subtile (rg, cg): 16x16 over K=64
        bf16x8 b0 = *(const bf16x8*)&sK[cg * 16 + l15][q8];
        bf16x8 b1 = *(const bf16x8*)&sK[cg * 16 + l15][32 + q8];
        f32x4 c = {0.f, 0.f, 0.f, 0.f};
        c = __builtin_amdgcn_mfma_f32_16x16x32_bf16(qa0, b0, c, 0, 0, 0);
        c = __builtin_amdgcn_mfma_f32_16x16x32_bf16(qa1, b1, c, 0, 0, 0);
        const int colg = kt * 64 + cg * 16 + l15;    // global col
#pragma unroll
        for (int r = 0; r < 4; ++r) {
            const int rowg = qs + rg * 16 + quad * 4 + r;
            float pr = (colg <= rowg) ? __expf(c[r] * INV_TEMP) : 0.f;
            rs[r] += pr;                             // f32 sum (matches kernel B's exp)
            sPt[rg * 16 + quad * 4 + r][cg * 16 + l15] = f2bf(pr);
        }
        __syncthreads();   // cross-wave P columns ready
        // PV: O(rg,cg) += P(rg, tile) . V(tile, cg)
#pragma unroll
        for (int kc = 0; kc < 2; ++kc) {
            bf16x8 a  = *(const bf16x8*)&sPt[rg * 16 + l15][kc * 32 + q8];
            bf16x8 vf = *(const bf16x8*)&sV[cg * 16 + l15][kc * 32 + q8];
            o = __builtin_amdgcn_mfma_f32_16x16x32_bf16(a, vf, o, 0, 0, 0);
        }
    }

    // ---- row-sum reduction: lanes (cols) -> waves (col-groups) ----
#pragma unroll
    for (int r = 0; r < 4; ++r) {
        float s = rs[r];
        s += __shfl_xor(s, 1);
        s += __shfl_xor(s, 2);
        s += __shfl_xor(s, 4);
        s += __shfl_xor(s, 8);
        rs[r] = s;
    }
    if (l15 == 0) {
#pragma unroll
        for (int r = 0; r < 4; ++r) rsum[w * 16 + quad * 4 + r] = rs[r];
    }
    __syncthreads();
    if (t < 32) {
        const int rg2 = t >> 4, rl = t & 15;
        float tot = rsum[(rg2 + 0) * 16 + rl] + rsum[(rg2 + 2) * 16 + rl]
                  + rsum[(rg2 + 4) * 16 + rl] + rsum[(rg2 + 6) * 16 + rl];
        sinv[t] = 1.f / tot;
        invws[(size_t)b * N + qs + t] = sinv[t];
    }
    __syncthreads();

    // ---- write O (normalized) ----
#pragma unroll
    for (int r = 0; r < 4; ++r) {
        const int rowl = rg * 16 + quad * 4 + r;
        out[(size_t)(b * N + qs + rowl) * D + cg * 16 + l15] = o[r] * sinv[rowl];
    }
}

// ---------------------------------------------------------------------------
// Kernel B: attn writer. Swapped-operand MFMA -> float4 row-contiguous stores,
// no barriers in the k-loop.
// ---------------------------------------------------------------------------
__global__ __launch_bounds__(512) void sdpa_attn(
    const float* __restrict__ q,
    const float* __restrict__ k,
    const float* __restrict__ attn_unused, // (kept for signature clarity)
    float* __restrict__ attn,
    const float* __restrict__ invws)
{
    __shared__ __align__(16) short sQ[32][72];
    __shared__ float sinv[32];

    const int x = blockIdx.x;
    const int b = x >> 6;
    const int u = x & 63;
    const int rt = 63 - u;
    const int qs = rt * 32;
    const int ntiles = (rt >> 1) + 1;

    const int t    = threadIdx.x;
    const int w    = t >> 6;
    const int lane = t & 63;
    const int l15  = lane & 15;
    const int quad = lane >> 4;
    const int q8   = quad * 8;
    const int rg   = w & 1;               // q row-group of 16
    const int cg   = w >> 1;              // k col-group of 16 within 64-wide tile

    const float* qb = q + (size_t)b * N * D;
    const float* kb = k + (size_t)b * N * D;
    float* attn_b = attn + (size_t)b * N * N;

    // ---- stage Q tile (identical bf16 rounding to kernel A) ----
    if (t < 256) {
        const int krow = t >> 3, kc8 = (t & 7) * 8;
        const float4* s = (const float4*)(qb + (size_t)(qs + krow) * D + kc8);
        float4 a = s[0], c4 = s[1];
        float qv[8] = {a.x,a.y,a.z,a.w, c4.x,c4.y,c4.z,c4.w};
        bf16x8 pq;
#pragma unroll
        for (int i = 0; i < 8; ++i) pq[i] = f2bf(qv[i]);
        *(bf16x8*)&sQ[krow][kc8] = pq;
    }
    if (t >= 256 && t < 288) sinv[t - 256] = invws[(size_t)b * N + qs + (t - 256)];
    __syncthreads();

    const bf16x8 qa0 = *(const bf16x8*)&sQ[rg * 16 + l15][q8];
    const bf16x8 qa1 = *(const bf16x8*)&sQ[rg * 16 + l15][32 + q8];

    const int qrow = qs + rg * 16 + l15;          // this lane's q-row (global)
    const float einv = sinv[rg * 16 + l15];
    float* arow = attn_b + (size_t)qrow * N;

    for (int kt = 0; kt < ntiles; ++kt) {
        // K-frags straight from global f32 (L2-resident), convert to bf16
        const float* kr = kb + (size_t)(kt * 64 + cg * 16 + l15) * D;
        const float4* kp = (const float4*)(kr + q8);
        float4 k0 = kp[0], k1 = kp[1];
        const float4* kp2 = (const float4*)(kr + 32 + q8);
        float4 k2 = kp2[0], k3 = kp2[1];
        float kv[16] = {k0.x,k0.y,k0.z,k0.w, k1.x,k1.y,k1.z,k1.w,
                        k2.x,k2.y,k2.z,k2.w, k3.x,k3.y,k3.z,k3.w};
        bf16x8 kb0, kb1;
#pragma unroll
        for (int i = 0; i < 8; ++i) { kb0[i] = f2bf(kv[i]); kb1[i] = f2bf(kv[8 + i]); }

        // swapped operands: C = K . Q^T = S^T  -> lane holds S[k0..k0+3][qrow]
        f32x4 c = {0.f, 0.f, 0.f, 0.f};
        c = __builtin_amdgcn_mfma_f32_16x16x32_bf16(kb0, qa0, c, 0, 0, 0);
        c = __builtin_amdgcn_mfma_f32_16x16x32_bf16(kb1, qa1, c, 0, 0, 0);

        const int kg0 = kt * 64 + cg * 16 + quad * 4; // first of 4 consecutive k
        float4 pv;
        pv.x = (kg0 + 0 <= qrow) ? __expf(c[0] * INV_TEMP) * einv : 0.f;
        pv.y = (kg0 + 1 <= qrow) ? __expf(c[1] * INV_TEMP) * einv : 0.f;
        pv.z = (kg0 + 2 <= qrow) ? __expf(c[2] * INV_TEMP) * einv : 0.f;
        pv.w = (kg0 + 3 <= qrow) ? __expf(c[3] * INV_TEMP) * einv : 0.f;
        *(float4*)(arow + kg0) = pv;
    }

    // ---- zero tail: cols [ntiles*64, N), fully coalesced ----
    const int lim  = ntiles * 64;
    const int erow = t >> 4;              // 0..31
    const int ec   = (t & 15) * 4;
    float* zrow = attn_b + (size_t)(qs + erow) * N;
    const float4 z = {0.f, 0.f, 0.f, 0.f};
    for (int c0 = lim + ec; c0 < N; c0 += 64) {
        *(float4*)(zrow + c0) = z;
    }
}

extern "C" void kernel_launch(void* const* d_in, const int* in_sizes, int n_in,
                              void* d_out, int out_size, void* d_ws, size_t ws_size,
                              hipStream_t stream) {
    const float* q = (const float*)d_in[0];
    const float* k = (const float*)d_in[1];
    const float* v = (const float*)d_in[2];
    // d_in[3] (mask) is static causal — not read.

    float* out  = (float*)d_out;
    float* attn = out + (size_t)B * N * D;
    float* invws = (float*)d_ws;          // B*N floats = 128 KB

    sdpa_flash<<<dim3(B * 64), dim3(512), 0, stream>>>(q, k, v, out, invws);
    sdpa_attn <<<dim3(B * 64), dim3(512), 0, stream>>>(q, k, attn, attn, invws);
}

// Round 3
// 471.601 us; speedup vs baseline: 1.1369x; 1.1369x over previous
//
#include <hip/hip_runtime.h>

// ScaledDotProductAttention: b=16, n=2048, d=64, causal, temp=8.
// Outputs concatenated in d_out: out [b,n,d] fp32, attn [b,n,n] fp32.
//
// Round 5: fused, perfectly-balanced kernel.
//  - 512 uniform blocks (512 thr / 8 waves). Block u handles TWO 32-row
//    q-tiles: rt=63-u (heavy) and rt=u (light) -> exactly 33 K-tiles and
//    512 KB of attn writes per block. 2 blocks/CU, no load imbalance.
//  - Per row-tile: flash phase (dbuf K/V staging, 2 barriers/tile, bf16
//    MFMA QK^T + PV, f32 row sums) then attn-stream phase (swapped-operand
//    MFMA reusing the SAME Q register fragments -> lane holds 4 consecutive
//    k of one q-row -> float4 coalesced stores, zero barriers).
//  - XCD-affinity wgid swizzle: each XCD's blocks cover exactly 2 batches,
//    so K/V are L2-resident (2 MB/XCD).

constexpr int B = 16;
constexpr int N = 2048;
constexpr int D = 64;
constexpr float INV_TEMP = 0.125f; // 1/8

typedef __attribute__((ext_vector_type(8))) short bf16x8; // 8 bf16 in 4 VGPRs
typedef __attribute__((ext_vector_type(4))) float f32x4;

__device__ __forceinline__ short f2bf(float f) {
    __bf16 h = (__bf16)f;
    return __builtin_bit_cast(short, h);
}

__global__ __launch_bounds__(512) void sdpa_fused2(
    const float* __restrict__ q,
    const float* __restrict__ k,
    const float* __restrict__ v,
    float* __restrict__ out,
    float* __restrict__ attn)
{
    __shared__ __align__(16) short sK[2][64][72];  // K tile, double-buffered
    __shared__ __align__(16) short sV[2][64][72];  // V^T tile: sV[buf][d][kr]
    __shared__ __align__(16) short sPt[32][72];    // Q stage, then per-tile P
    __shared__ float rsum[128];                    // [8 waves][16 rows]
    __shared__ float sinv[32];

    // XCD-affinity swizzle: wgid%8 = XCD (round-robin dispatch) -> give each
    // XCD two full batches so K/V stay L2-resident.
    const int x   = blockIdx.x;
    const int xcd = x & 7;
    const int idx = x >> 3;               // 0..63
    const int b   = xcd * 2 + (idx & 1);  // batch
    const int u   = idx >> 1;             // 0..31

    const int t    = threadIdx.x;
    const int w    = t >> 6;              // wave 0..7
    const int lane = t & 63;
    const int l15  = lane & 15;
    const int quad = lane >> 4;           // 0..3
    const int q8   = quad * 8;
    const int rg   = w & 1;               // row-group (16 rows) of the 32-row tile
    const int cg   = w >> 1;              // col-group (16 cols) of the 64-col K tile

    const float* qb = q + (size_t)b * N * D;
    const float* kb = k + (size_t)b * N * D;
    const float* vb = v + (size_t)b * N * D;
    float* attn_b = attn + (size_t)b * N * N;

    const int krow = t >> 3;              // staging row 0..63
    const int kc8  = (t & 7) * 8;         // staging d-chunk start (8 floats)

    for (int h = 0; h < 2; ++h) {
        const int rt = h ? u : (63 - u);  // heavy tile first
        const int qs = rt * 32;
        const int nt = (rt >> 1) + 1;     // 64-wide K tiles covering cols 0..qs+31

        // ---- prefetch K/V tile 0 into registers (independent global loads) ----
        float4 kf0, kf1;
        float  vr[8];
        {
            const float4* s = (const float4*)(kb + (size_t)krow * D + kc8);
            kf0 = s[0]; kf1 = s[1];
            const float* sv = vb + (size_t)(w * 8) * D + lane;
#pragma unroll
            for (int i = 0; i < 8; ++i) vr[i] = sv[(size_t)i * D];
        }

        __syncthreads();   // all waves done with previous phase (sPt free)
        // ---- stage Q tile -> sPt (bf16), load A-frags to registers ----
        if (t < 256) {
            const float4* s = (const float4*)(qb + (size_t)(qs + krow) * D + kc8);
            float4 a = s[0], c4 = s[1];
            float qv[8] = {a.x,a.y,a.z,a.w, c4.x,c4.y,c4.z,c4.w};
            bf16x8 pq;
#pragma unroll
            for (int i = 0; i < 8; ++i) pq[i] = f2bf(qv[i]);
            *(bf16x8*)&sPt[krow][kc8] = pq;
        }
        __syncthreads();
        const bf16x8 qa0 = *(const bf16x8*)&sPt[rg * 16 + l15][q8];       // d 0..31
        const bf16x8 qa1 = *(const bf16x8*)&sPt[rg * 16 + l15][32 + q8];  // d 32..63

        float rs[4] = {0.f, 0.f, 0.f, 0.f};
        f32x4 o = {0.f, 0.f, 0.f, 0.f};

        // ---- flash phase: 2 barriers per tile (dbuf staging) ----
        for (int kt = 0; kt < nt; ++kt) {
            const int cur = kt & 1;
            {   // staged regs -> LDS (b128 writes into the idle buffer)
                float kv[8] = {kf0.x,kf0.y,kf0.z,kf0.w, kf1.x,kf1.y,kf1.z,kf1.w};
                bf16x8 pk, pv;
#pragma unroll
                for (int i = 0; i < 8; ++i) pk[i] = f2bf(kv[i]);
#pragma unroll
                for (int i = 0; i < 8; ++i) pv[i] = f2bf(vr[i]);
                *(bf16x8*)&sK[cur][krow][kc8]  = pk;   // K[kr][d]
                *(bf16x8*)&sV[cur][lane][w*8]  = pv;   // V^T: sV[d][kr]
            }
            __syncthreads();  // staging visible; prev PV + (kt=0) Q-frag reads done
            // T14: issue next tile's global loads; latency hides under S+PV
            if (kt + 1 < nt) {
                const float4* s = (const float4*)(kb + (size_t)((kt+1)*64 + krow) * D + kc8);
                kf0 = s[0]; kf1 = s[1];
                const float* sv = vb + (size_t)((kt+1)*64 + w*8) * D + lane;
#pragma unroll
                for (int i = 0; i < 8; ++i) vr[i] = sv[(size_t)i * D];
            }
            // S subtile (rg, cg): 16x16 over K=64
            bf16x8 b0 = *(const bf16x8*)&sK[cur][cg * 16 + l15][q8];
            bf16x8 b1 = *(const bf16x8*)&sK[cur][cg * 16 + l15][32 + q8];
            f32x4 c = {0.f, 0.f, 0.f, 0.f};
            c = __builtin_amdgcn_mfma_f32_16x16x32_bf16(qa0, b0, c, 0, 0, 0);
            c = __builtin_amdgcn_mfma_f32_16x16x32_bf16(qa1, b1, c, 0, 0, 0);
            const int colg = kt * 64 + cg * 16 + l15;
#pragma unroll
            for (int r = 0; r < 4; ++r) {
                const int rowg = qs + rg * 16 + quad * 4 + r;
                float pr = (colg <= rowg) ? __expf(c[r] * INV_TEMP) : 0.f;
                rs[r] += pr;
                sPt[rg * 16 + quad * 4 + r][cg * 16 + l15] = f2bf(pr);
            }
            __syncthreads();  // cross-wave P columns ready
            // PV: O(rg,cg) += P(rg, tile) . V(tile, cg)
#pragma unroll
            for (int kc = 0; kc < 2; ++kc) {
                bf16x8 a  = *(const bf16x8*)&sPt[rg * 16 + l15][kc * 32 + q8];
                bf16x8 vf = *(const bf16x8*)&sV[cur][cg * 16 + l15][kc * 32 + q8];
                o = __builtin_amdgcn_mfma_f32_16x16x32_bf16(a, vf, o, 0, 0, 0);
            }
        }

        // ---- row-sum reduction ----
#pragma unroll
        for (int r = 0; r < 4; ++r) {
            float s = rs[r];
            s += __shfl_xor(s, 1);
            s += __shfl_xor(s, 2);
            s += __shfl_xor(s, 4);
            s += __shfl_xor(s, 8);
            rs[r] = s;
        }
        if (l15 == 0) {
#pragma unroll
            for (int r = 0; r < 4; ++r) rsum[w * 16 + quad * 4 + r] = rs[r];
        }
        __syncthreads();
        if (t < 32) {
            const int rg2 = t >> 4, rl = t & 15;
            float tot = rsum[(rg2 + 0) * 16 + rl] + rsum[(rg2 + 2) * 16 + rl]
                      + rsum[(rg2 + 4) * 16 + rl] + rsum[(rg2 + 6) * 16 + rl];
            sinv[t] = 1.f / tot;
        }
        __syncthreads();

        // ---- write O (normalized) ----
#pragma unroll
        for (int r = 0; r < 4; ++r) {
            const int rowl = rg * 16 + quad * 4 + r;
            out[(size_t)(b * N + qs + rowl) * D + cg * 16 + l15] = o[r] * sinv[rowl];
        }

        // ---- attn-stream phase: swapped-operand MFMA, no barriers ----
        // Q A-frags double as the swapped B-operand (identical lane layout).
        const int qrow = qs + rg * 16 + l15;      // this lane's q-row (global)
        const float einv = sinv[rg * 16 + l15];
        float* arow = attn_b + (size_t)qrow * N;

        float4 ka0, ka1, ka2, ka3;                // K prefetch regs (16 floats)
        {
            const float* kr = kb + (size_t)(cg * 16 + l15) * D;
            const float4* kp = (const float4*)(kr + q8);
            ka0 = kp[0]; ka1 = kp[1];
            const float4* kp2 = (const float4*)(kr + 32 + q8);
            ka2 = kp2[0]; ka3 = kp2[1];
        }
        for (int kt = 0; kt < nt; ++kt) {
            float kv[16] = {ka0.x,ka0.y,ka0.z,ka0.w, ka1.x,ka1.y,ka1.z,ka1.w,
                            ka2.x,ka2.y,ka2.z,ka2.w, ka3.x,ka3.y,ka3.z,ka3.w};
            bf16x8 kb0, kb1;
#pragma unroll
            for (int i = 0; i < 8; ++i) { kb0[i] = f2bf(kv[i]); kb1[i] = f2bf(kv[8 + i]); }
            if (kt + 1 < nt) {   // prefetch next tile's K rows (L2-hot)
                const float* kr = kb + (size_t)((kt+1)*64 + cg * 16 + l15) * D;
                const float4* kp = (const float4*)(kr + q8);
                ka0 = kp[0]; ka1 = kp[1];
                const float4* kp2 = (const float4*)(kr + 32 + q8);
                ka2 = kp2[0]; ka3 = kp2[1];
            }
            // swapped operands: C = K . Q^T = S^T -> lane holds S[k0..k0+3][qrow]
            f32x4 c = {0.f, 0.f, 0.f, 0.f};
            c = __builtin_amdgcn_mfma_f32_16x16x32_bf16(kb0, qa0, c, 0, 0, 0);
            c = __builtin_amdgcn_mfma_f32_16x16x32_bf16(kb1, qa1, c, 0, 0, 0);

            const int kg0 = kt * 64 + cg * 16 + quad * 4;
            float4 pv4;
            pv4.x = (kg0 + 0 <= qrow) ? __expf(c[0] * INV_TEMP) * einv : 0.f;
            pv4.y = (kg0 + 1 <= qrow) ? __expf(c[1] * INV_TEMP) * einv : 0.f;
            pv4.z = (kg0 + 2 <= qrow) ? __expf(c[2] * INV_TEMP) * einv : 0.f;
            pv4.w = (kg0 + 3 <= qrow) ? __expf(c[3] * INV_TEMP) * einv : 0.f;
            *(float4*)(arow + kg0) = pv4;
        }

        // ---- zero tail: cols [nt*64, N), fully coalesced ----
        const int lim  = nt * 64;
        const int erow = t >> 4;              // 0..31
        const int ec   = (t & 15) * 4;
        float* zrow = attn_b + (size_t)(qs + erow) * N;
        const float4 z = {0.f, 0.f, 0.f, 0.f};
        for (int c0 = lim + ec; c0 < N; c0 += 64) {
            *(float4*)(zrow + c0) = z;
        }
    }
}

extern "C" void kernel_launch(void* const* d_in, const int* in_sizes, int n_in,
                              void* d_out, int out_size, void* d_ws, size_t ws_size,
                              hipStream_t stream) {
    const float* q = (const float*)d_in[0];
    const float* k = (const float*)d_in[1];
    const float* v = (const float*)d_in[2];
    // d_in[3] (mask) is static causal — not read.

    float* out  = (float*)d_out;
    float* attn = out + (size_t)B * N * D;

    sdpa_fused2<<<dim3(B * 32), dim3(512), 0, stream>>>(q, k, v, out, attn);
}